// Round 3
// baseline (170.530 us; speedup 1.0000x reference)
//
#include <hip/hip_runtime.h>
#include <math.h>

// input (32,3,128,128) f32; output (32,3,512,512) f32.
// loss = mean |bicubic_down4(output) - input|, 16-tap separable, symmetric pad 6.
#define BCN   96
#define IN_H  512
#define IN_W  512
#define OUT_H 128
#define OUT_W 128
#define TAPS  16
#define PAD   6
#define STRIDE 4
#define TR    8                          // output rows per block
#define IR    ((TR - 1) * STRIDE + TAPS) // 44 input rows per tile
#define NCH   (IR / 4)                   // 11 chunks of 4 raw rows
#define NBLK  (BCN * (OUT_H / TR))       // 1536 blocks
#define TOTAL_ELEMS (BCN * OUT_H * OUT_W)

struct K16 { float w[TAPS]; };

__device__ __forceinline__ int sym_idx(int i, int n) {
    i = (i < 0) ? (-1 - i) : i;
    return (i >= n) ? (2 * n - 1 - i) : i;
}

// LDS XOR-swizzle (involution): toggle 16B-block bit (bit4) with bit7.
// Spreads 32B-lane-stride ds_read_b128 across all 32 banks.
__device__ __forceinline__ int swz(int b) { return b ^ (((b >> 7) & 1) << 4); }

__global__ __launch_bounds__(256)
void bploss_kernel(const float* __restrict__ input,   // (96,128,128)
                   const float* __restrict__ outimg,  // (96,512,512)
                   float* __restrict__ loss, K16 kwa)
{
    __shared__ float dbuf[2][4 * IN_W];  // raw 4-row chunks, swizzled; 2 x 8KB
    __shared__ float hrow[4][OUT_W];     // h-conv output of current chunk, 2KB
    __shared__ float kwl[TAPS];
    __shared__ float wsum[4];

    const int tid  = threadIdx.x;
    const int bc   = blockIdx.x >> 4;
    const int tile = blockIdx.x & 15;
    const int r0   = tile * TR;
    const int iy0  = r0 * STRIDE - PAD;

    const float* img = outimg + (size_t)bc * IN_H * IN_W;

    // staging: 8KB chunk = 512 slots of 16B; slot s -> row s>>7, float col (s&127)*4
    auto gsrc = [&](int ch, int s) -> const float4* {
        const int y = sym_idx(iy0 + ch * 4 + (s >> 7), IN_H);
        return reinterpret_cast<const float4*>(img + (size_t)y * IN_W + (s & 127) * 4);
    };
    auto lslot = [&](float* buf, int s) -> float4* {
        return reinterpret_cast<float4*>(reinterpret_cast<char*>(buf) + swz(s << 4));
    };

    // ---- prologue: stage chunk 0, copy weights to LDS ----
    {
        float4 a = *gsrc(0, tid);
        float4 b = *gsrc(0, tid + 256);
        *lslot(dbuf[0], tid)       = a;
        *lslot(dbuf[0], tid + 256) = b;
    }
    if (tid < TAPS) kwl[tid] = kwa.w[tid];
    __syncthreads();

    // roles
    const int pr = tid >> 6;             // h-conv: raw row in chunk 0..3
    const int c  = tid & 63;             // h-conv: col-pair (xo = 2c, 2c+1)
    const int vb = tid >> 7;             // v-accum: row-group 0..1 (yl = 4*vb+k)
    const int vx = tid & 127;            // v-accum: column

    int f0 = 8 * c - 8;                  // window start (float idx), 16B aligned
    f0 = (f0 < 0) ? 0 : f0;
    f0 = (f0 > 488) ? 488 : f0;
    const int Lbase = pr * (IN_W * 4) + f0 * 4;   // logical byte in chunk

    float vacc[4] = {0.f, 0.f, 0.f, 0.f};

    for (int ch = 0; ch < NCH; ++ch) {
        // -- issue next chunk's global loads early (latency hides under h-conv)
        const int chn = (ch + 1 < NCH) ? (ch + 1) : (NCH - 1);
        const float4 n0 = *gsrc(chn, tid);
        const float4 n1 = *gsrc(chn, tid + 256);

        // -- horizontal conv from swizzled LDS (6x ds_read_b128, all banks) --
        const char* raw = reinterpret_cast<const char*>(dbuf[ch & 1]);
        const float4 w0 = *reinterpret_cast<const float4*>(raw + swz(Lbase));
        const float4 w1 = *reinterpret_cast<const float4*>(raw + swz(Lbase + 16));
        const float4 w2 = *reinterpret_cast<const float4*>(raw + swz(Lbase + 32));
        const float4 w3 = *reinterpret_cast<const float4*>(raw + swz(Lbase + 48));
        const float4 w4 = *reinterpret_cast<const float4*>(raw + swz(Lbase + 64));
        const float4 w5 = *reinterpret_cast<const float4*>(raw + swz(Lbase + 80));
        const float win[24] = { w0.x,w0.y,w0.z,w0.w, w1.x,w1.y,w1.z,w1.w,
                                w2.x,w2.y,w2.z,w2.w, w3.x,w3.y,w3.z,w3.w,
                                w4.x,w4.y,w4.z,w4.w, w5.x,w5.y,w5.z,w5.w };
        float acc0 = 0.f, acc1 = 0.f;
        #pragma unroll
        for (int t = 0; t < TAPS; ++t) {
            acc0 += kwa.w[t] * win[t + 2];   // xo=2c
            acc1 += kwa.w[t] * win[t + 6];   // xo=2c+1
        }
        // boundary lanes: static-index recompute with symmetric reflection
        if (c == 0) {           // f0=0: win[i] = col i
            float a0 = 0.f, a1 = 0.f;
            #pragma unroll
            for (int t = 0; t < TAPS; ++t) {
                const int i0 = (t < 6) ? (5 - t) : (t - 6);   // xo=0
                const int i1 = (t < 2) ? (1 - t) : (t - 2);   // xo=1
                a0 += kwa.w[t] * win[i0];
                a1 += kwa.w[t] * win[i1];
            }
            acc0 = a0; acc1 = a1;
        } else if (c == 63) {   // f0=488: win[i] = col 488+i
            float a0 = 0.f, a1 = 0.f;
            #pragma unroll
            for (int t = 0; t < TAPS; ++t) {
                const int i0 = (t <= 13) ? (10 + t) : ((t == 14) ? 23 : 22); // xo=126
                const int i1 = (t <= 9) ? (14 + t) : (33 - t);               // xo=127
                a0 += kwa.w[t] * win[i0];
                a1 += kwa.w[t] * win[i1];
            }
            acc0 = a0; acc1 = a1;
        }
        *reinterpret_cast<float2*>(&hrow[pr][2 * c]) = make_float2(acc0, acc1);

        __syncthreads();   // hrow ready; staged loads n0/n1 drained here too

        // -- vertical accumulate: chunk ch gives taps t0..t0+3 to yl in [ch-3,ch]
        const float h0 = hrow[0][vx], h1 = hrow[1][vx],
                    h2 = hrow[2][vx], h3 = hrow[3][vx];
        #pragma unroll
        for (int k = 0; k < 4; ++k) {
            const int t0 = 4 * (ch - (4 * vb + k));   // wave-uniform branch
            if (t0 >= 0 && t0 < TAPS) {
                vacc[k] += kwl[t0] * h0 + kwl[t0 + 1] * h1
                         + kwl[t0 + 2] * h2 + kwl[t0 + 3] * h3;
            }
        }

        // -- write next chunk into other buffer (loads long since in flight) --
        *lslot(dbuf[(ch + 1) & 1], tid)       = n0;
        *lslot(dbuf[(ch + 1) & 1], tid + 256) = n1;
        __syncthreads();
    }

    // ---- epilogue: |diff| vs input + reduction ----
    float lsum = 0.f;
    #pragma unroll
    for (int k = 0; k < 4; ++k) {
        const int yo = r0 + 4 * vb + k;
        const float ref = input[((size_t)bc * OUT_H + yo) * OUT_W + vx];
        lsum += fabsf(vacc[k] - ref);
    }

    #pragma unroll
    for (int off = 32; off > 0; off >>= 1)
        lsum += __shfl_down(lsum, off, 64);

    const int wid = tid >> 6, lane = tid & 63;
    if (lane == 0) wsum[wid] = lsum;
    __syncthreads();
    if (tid == 0) {
        const float s = wsum[0] + wsum[1] + wsum[2] + wsum[3];
        atomicAdd(loss, s * (1.0f / (float)TOTAL_ELEMS));
    }
}

static void make_weights(K16* kw) {
    const double scale = 0.25;
    double w[TAPS]; double s = 0.0;
    for (int t = 0; t < TAPS; ++t) {
        const double ax = fabs((7.5 - (double)t) * scale);
        double v;
        if (ax <= 1.0)      v = 1.5 * ax * ax * ax - 2.5 * ax * ax + 1.0;
        else if (ax <= 2.0) v = -0.5 * ax * ax * ax + 2.5 * ax * ax - 4.0 * ax + 2.0;
        else                v = 0.0;
        w[t] = v * scale; s += w[t];
    }
    for (int t = 0; t < TAPS; ++t) kw->w[t] = (float)(w[t] / s);
}

extern "C" void kernel_launch(void* const* d_in, const int* in_sizes, int n_in,
                              void* d_out, int out_size, void* d_ws, size_t ws_size,
                              hipStream_t stream) {
    const float* input;
    const float* outimg;
    if (in_sizes[0] == TOTAL_ELEMS) {
        input  = (const float*)d_in[0];
        outimg = (const float*)d_in[1];
    } else {
        input  = (const float*)d_in[1];
        outimg = (const float*)d_in[0];
    }
    float* loss = (float*)d_out;

    K16 kw;
    make_weights(&kw);

    hipMemsetAsync(d_out, 0, sizeof(float), stream);
    bploss_kernel<<<NBLK, 256, 0, stream>>>(input, outimg, loss, kw);
}